// Round 10
// baseline (647.457 us; speedup 1.0000x reference)
//
#include <hip/hip_runtime.h>
#include <hip/hip_bf16.h>
#include <math.h>

#define NNODES   50000
#define INDIM    78
#define NHEADS   10
#define CDIM     78
#define HCDIM    780
#define NEDGES   400000
#define NBATCH   256
#define ETOT     (NEDGES + NNODES)   // 450000, with self-loops
#define NEG_SLOPE 0.2f

// GEMM2 MFMA tiling
#define BM 128
#define BN 128
#define BK 64             // K-tile (13 iters over KPAD)
#define KPAD 832          // 13 * 64
#define NPAD 896          // 7 * 128
#define LDT 68            // transposed epilogue tile stride (ushorts)

// GEMM1 (fused xl|xr) tiling
#define KP1 128           // 78 padded to 4*32
#define NP1 1664          // 13 * 128  (780 xl | 780 xr | pad)

typedef __attribute__((ext_vector_type(8))) short bf16x8_t;
typedef __attribute__((ext_vector_type(4))) float f32x4_t;
typedef __attribute__((ext_vector_type(2))) float v2f;

__device__ __forceinline__ float bf2f(unsigned short u) {
    union { unsigned int i; float f; } v; v.i = ((unsigned int)u) << 16; return v.f;
}
__device__ __forceinline__ unsigned short f2bf(float f) {
    __hip_bfloat16 h = __float2bfloat16(f);
    return *reinterpret_cast<unsigned short*>(&h);
}
// packed pair of bf16 (even channel in low half) -> v2f
__device__ __forceinline__ v2f cvt2(unsigned int u) {
    union { unsigned int i; float f; } lo, hi;
    lo.i = u << 16;
    hi.i = u & 0xFFFF0000u;
    v2f r; r.x = lo.f; r.y = hi.f; return r;
}
__device__ __forceinline__ v2f vabs2(v2f t) {
    union { v2f f; unsigned long long u; } x; x.f = t;
    x.u &= 0x7FFFFFFF7FFFFFFFull; return x.f;
}
// sum over each 8-lane group via DPP (3 steps, no LDS)
__device__ __forceinline__ float dpp_red8(float x) {
    int y;
    y = __builtin_amdgcn_update_dpp(0, __float_as_int(x), 0xB1, 0xF, 0xF, true);   // quad_perm xor1
    x += __int_as_float(y);
    y = __builtin_amdgcn_update_dpp(0, __float_as_int(x), 0x4E, 0xF, 0xF, true);   // quad_perm xor2
    x += __int_as_float(y);
    y = __builtin_amdgcn_update_dpp(0, __float_as_int(x), 0x141, 0xF, 0xF, true);  // row_half_mirror
    x += __int_as_float(y);
    return x;
}

// async global->LDS, 16 B per lane; LDS base wave-uniform (HW: base+lane*16)
__device__ __forceinline__ void async_ld16(const unsigned short* g, unsigned short* l) {
    __builtin_amdgcn_global_load_lds(
        (const __attribute__((address_space(1))) void*)g,
        (__attribute__((address_space(3))) void*)l, 16, 0, 0);
}

// ---------------------------------------------------------------------------
// zero-init (out for atomics + deg for CSR) in one launch
// ---------------------------------------------------------------------------
__global__ void zero_kernel(float* __restrict__ outp, int nf, int* __restrict__ deg, int ni) {
    int i = blockIdx.x * blockDim.x + threadIdx.x;
    if (i < nf) outp[i] = 0.f;
    if (i < ni) deg[i] = 0;
}

// ---------------------------------------------------------------------------
// CSR build
// ---------------------------------------------------------------------------
__global__ void count_kernel(const int* __restrict__ ei, int* __restrict__ deg) {
    int e = blockIdx.x * blockDim.x + threadIdx.x;
    if (e >= ETOT) return;
    int d = (e < NEDGES) ? ei[NEDGES + e] : (e - NEDGES);
    atomicAdd(&deg[d], 1);
}

__global__ void scan1_kernel(const int* __restrict__ deg, int* __restrict__ rowp,
                             int* __restrict__ bsum) {
    __shared__ int s[256];
    int t = threadIdx.x, b = blockIdx.x;
    int i = b * 256 + t;
    int v = (i < NNODES) ? deg[i] : 0;
    s[t] = v;
    __syncthreads();
    #pragma unroll
    for (int off = 1; off < 256; off <<= 1) {
        int y = (t >= off) ? s[t - off] : 0;
        __syncthreads();
        s[t] += y;
        __syncthreads();
    }
    int incl = s[t];
    if (i < NNODES) rowp[i] = incl - v;
    if (t == 255) bsum[b] = incl;
}

__global__ void scan2_kernel(int* __restrict__ bsum, int* __restrict__ rowp, int nblk,
                             const int* __restrict__ batch, int* __restrict__ bst) {
    __shared__ int s[256];
    int t = threadIdx.x;
    int v = 0;
    if (t < 256) { v = (t < nblk) ? bsum[t] : 0; s[t] = v; }
    __syncthreads();
    #pragma unroll
    for (int off = 1; off < 256; off <<= 1) {
        int y = (t < 256 && t >= off) ? s[t - off] : 0;
        __syncthreads();
        if (t < 256) s[t] += y;
        __syncthreads();
    }
    if (t < 256) {
        int incl = s[t];
        if (t < nblk) bsum[t] = incl - v;
        if (t == 255) rowp[NNODES] = incl;
    } else {
        int b = t - 256;
        int lo = 0, hi = NNODES;
        while (lo < hi) { int mid = (lo + hi) >> 1; if (batch[mid] < b) lo = mid + 1; else hi = mid; }
        bst[b] = lo;
        if (t == 511) bst[NBATCH] = NNODES;
    }
}

__global__ void scan3_kernel(int* __restrict__ rowp, const int* __restrict__ bsum,
                             int* __restrict__ curs, const int* __restrict__ deg,
                             float* __restrict__ dinv) {
    int i = blockIdx.x * 256 + threadIdx.x;
    if (i >= NNODES) return;
    int r = rowp[i] + bsum[i >> 8];
    rowp[i] = r;
    curs[i] = r;
    dinv[i] = rsqrtf((float)deg[i]);
}

__global__ void fill_kernel(const int* __restrict__ ei,
                            int* __restrict__ cursor, int* __restrict__ col) {
    int e = blockIdx.x * blockDim.x + threadIdx.x;
    if (e >= ETOT) return;
    int s, d;
    if (e < NEDGES) { s = ei[e]; d = ei[NEDGES + e]; }
    else            { s = d = e - NEDGES; }
    int pos = atomicAdd(&cursor[d], 1);
    col[pos] = s;
}

// ---------------------------------------------------------------------------
// Wc prep: Wc[n][k] = bf16([W_l|W_r]^T), zero-padded to [NP1][KP1]
// ---------------------------------------------------------------------------
__global__ void wprep_kernel(const float* __restrict__ Wl, const float* __restrict__ Wr,
                             unsigned short* __restrict__ Wc) {
    int idx = blockIdx.x * 256 + threadIdx.x;
    if (idx >= NP1 * KP1) return;
    int n = idx >> 7, k = idx & 127;
    float v = 0.f;
    if (k < INDIM) {
        if (n < HCDIM)            v = Wl[(size_t)k * HCDIM + n];
        else if (n < 2 * HCDIM)   v = Wr[(size_t)k * HCDIM + (n - HCDIM)];
    }
    Wc[idx] = f2bf(v);
}

// ---------------------------------------------------------------------------
// GEMM1 fused MFMA: [xl|xr] = x @ [W_l|W_r]  (bf16 out) — unchanged (rot swizzle)
// ---------------------------------------------------------------------------
__global__ __launch_bounds__(256) void gemm1_kernel(
        const float* __restrict__ x, const unsigned short* __restrict__ Wc,
        unsigned short* __restrict__ xl, unsigned short* __restrict__ xr, int M) {
    __shared__ unsigned short As[4 * 4096];
    __shared__ unsigned short Bs[4 * 4096];
    int t = threadIdx.x;
    int lane = t & 63, w = t >> 6;
    int bm = blockIdx.x * 128;

    for (int idx = t; idx < 128 * 128; idx += 256) {
        int row = idx >> 7, k = idx & 127;
        int kc = k >> 5, ch = (k >> 3) & 3, e = k & 7;
        int gr = bm + row;
        float v = (gr < M && k < INDIM) ? x[(size_t)gr * INDIM + k] : 0.f;
        As[kc * 4096 + row * 32 + (((ch + (row >> 1)) & 3) * 8) + e] = f2bf(v);
    }

    int lrow = lane >> 2;
    int gch = ((lane & 3) - (lane >> 3)) & 3;
    int m16 = lane & 15, q = lane >> 4;
    int wr = (w >> 1) * 64, wcc = (w & 1) * 64;

    for (int nb = 0; nb < 13; nb++) {
        __syncthreads();
        #pragma unroll
        for (int kc = 0; kc < 4; kc++) {
            const unsigned short* gb = Wc + ((size_t)(nb * 128 + 32 * w + lrow)) * KP1
                                          + kc * 32 + gch * 8;
            unsigned short* lb = Bs + kc * 4096 + (32 * w) * 32;
            async_ld16(gb, lb);
            async_ld16(gb + 16 * KP1, lb + 16 * 32);
        }
        __syncthreads();

        f32x4_t acc[4][4];
        #pragma unroll
        for (int i = 0; i < 4; i++)
            #pragma unroll
            for (int j = 0; j < 4; j++)
                acc[i][j] = (f32x4_t)(0.f);

        #pragma unroll
        for (int kc = 0; kc < 4; kc++) {
            bf16x8_t af[4], bf[4];
            #pragma unroll
            for (int i = 0; i < 4; i++) {
                int row = wr + i * 16 + m16;
                af[i] = *(const bf16x8_t*)&As[kc * 4096 + row * 32 + (((q + (row >> 1)) & 3) * 8)];
            }
            #pragma unroll
            for (int j = 0; j < 4; j++) {
                int row = wcc + j * 16 + m16;
                bf[j] = *(const bf16x8_t*)&Bs[kc * 4096 + row * 32 + (((q + (row >> 1)) & 3) * 8)];
            }
            #pragma unroll
            for (int i = 0; i < 4; i++)
                #pragma unroll
                for (int j = 0; j < 4; j++)
                    acc[i][j] = __builtin_amdgcn_mfma_f32_16x16x32_bf16(af[i], bf[j], acc[i][j], 0, 0, 0);
        }

        #pragma unroll
        for (int j = 0; j < 4; j++) {
            int ng = nb * 128 + wcc + j * 16 + m16;
            if (ng >= 2 * HCDIM) continue;
            unsigned short* dst = (ng < HCDIM) ? (xl + ng) : (xr + (ng - HCDIM));
            #pragma unroll
            for (int i = 0; i < 4; i++) {
                #pragma unroll
                for (int rr = 0; rr < 4; rr++) {
                    int row = bm + wr + i * 16 + q * 4 + rr;
                    if (row < M) dst[(size_t)row * HCDIM] = f2bf(acc[i][j][rr]);
                }
            }
        }
    }
}

// ---------------------------------------------------------------------------
// GATv2 aggregation v6: 8 lanes per head, 5 waves per 4 nodes.
//  slots 0-3: node 4q+slot, groups = heads 0-7; slot 4 (straddle): group g ->
//  node 4q+(g>>1), head 8+(g&1). Lane cl covers pairs cl+8k, k=0..4 (39 pairs;
//  cl=7,k=4 clamped to pair 38, masked out of score/store).
// att pre-scaled by 0.6*log2e / 0.4*log2e; p = exp2(part).
// Epilogue writes h' = dinv[node] * ELU(...) (GCN's dinv[j] pre-folded).
// ---------------------------------------------------------------------------
__global__ __launch_bounds__(256) void gat_kernel(
        const unsigned short* __restrict__ xl, const unsigned short* xr,
        const int* __restrict__ row_ptr, const int* __restrict__ col,
        const float* __restrict__ att, const float* __restrict__ bias1,
        const float* __restrict__ dinv, unsigned short* h_out) {
    int wid = blockIdx.x * 4 + (threadIdx.x >> 6);
    int quad = wid / 5;
    int slot = wid - 5 * quad;
    if (quad >= NNODES / 4) return;
    int lane = threadIdx.x & 63;
    int g = lane >> 3, cl = lane & 7;
    bool lo7 = cl < 7;
    bool strad = (slot == 4);
    int node, head;
    if (!strad) { node = 4 * quad + slot;      head = g; }
    else        { node = 4 * quad + (g >> 1);  head = 8 + (g & 1); }
    int hcl = head * (CDIM / 2);       // uint offset of head base (39)
    const unsigned int* xlu = (const unsigned int*)xl;
    const unsigned int* xru = (const unsigned int*)xr;

    int off[5];
    off[0] = cl; off[1] = cl + 8; off[2] = cl + 16; off[3] = cl + 24;
    off[4] = lo7 ? cl + 32 : 38;       // clamp; masked below

    const float L6 = 0.6f * 1.4426950408889634f;
    const float L4 = 0.4f * 1.4426950408889634f;
    const float2* ap = (const float2*)(att + head * CDIM);
    const unsigned int* xrp = xru + (size_t)node * (HCDIM / 2) + hcl;
    v2f a6[5], a4[5], r[5];
    #pragma unroll
    for (int k = 0; k < 5; k++) {
        float2 f = ap[off[k]];
        if (k == 4 && !lo7) { f.x = 0.f; f.y = 0.f; }
        a6[k].x = f.x * L6; a6[k].y = f.y * L6;
        a4[k].x = f.x * L4; a4[k].y = f.y * L4;
        r[k] = cvt2(xrp[off[k]]);
    }

    float l = 0.f;
    v2f acc[5];
    #pragma unroll
    for (int k = 0; k < 5; k++) acc[k] = (v2f)(0.f);

    if (!strad) {
        int e0 = row_ptr[node], e1 = row_ptr[node + 1];
        int e = e0;
        for (; e < e1; e++) {
            int j = __builtin_amdgcn_readfirstlane(col[e]);
            const unsigned int* xp = xlu + (size_t)j * (HCDIM / 2) + hcl;
            v2f v[5], s2 = (v2f)(0.f);
            #pragma unroll
            for (int k = 0; k < 5; k++) {
                v[k] = cvt2(xp[off[k]]);
                v2f t = v[k] + r[k];
                s2 += t * a6[k] + vabs2(t) * a4[k];
            }
            float p = __builtin_amdgcn_exp2f(dpp_red8(s2.x + s2.y));
            l += p;
            #pragma unroll
            for (int k = 0; k < 5; k++) acc[k] += p * v[k];
        }
    } else {
        int re0 = row_ptr[node], deg = row_ptr[node + 1] - re0;
        int d0 = __builtin_amdgcn_readlane(deg, 0);
        int d1 = __builtin_amdgcn_readlane(deg, 16);
        int d2 = __builtin_amdgcn_readlane(deg, 32);
        int d3 = __builtin_amdgcn_readlane(deg, 48);
        int iters = max(max(d0, d1), max(d2, d3));
        for (int i = 0; i < iters; i++) {
            bool live = i < deg;
            int ec = re0 + (live ? i : 0);     // clamped: stays in-bounds
            int j = col[ec];                   // uniform within group -> broadcast
            const unsigned int* xp = xlu + (size_t)j * (HCDIM / 2) + hcl;
            v2f v[5], s2 = (v2f)(0.f);
            #pragma unroll
            for (int k = 0; k < 5; k++) {
                v[k] = cvt2(xp[off[k]]);
                v2f t = v[k] + r[k];
                s2 += t * a6[k] + vabs2(t) * a4[k];
            }
            float p = __builtin_amdgcn_exp2f(dpp_red8(s2.x + s2.y));
            p = live ? p : 0.f;
            l += p;
            #pragma unroll
            for (int k = 0; k < 5; k++) acc[k] += p * v[k];
        }
    }

    float inv = 1.f / l;                   // l > 0 (self-loop)
    float dn = dinv[node];
    size_t rbase = (size_t)node * HCDIM + head * CDIM;
    const float2* bp = (const float2*)(bias1 + head * CDIM);
    unsigned int* op = (unsigned int*)(h_out + rbase);
    #pragma unroll
    for (int k = 0; k < 5; k++) {
        if (k == 4 && !lo7) break;
        float2 bb = bp[off[k]];
        float x0 = acc[k].x * inv + bb.x;
        float x1 = acc[k].y * inv + bb.y;
        x0 = x0 > 0.f ? x0 : (__expf(x0) - 1.f);   // ELU
        x1 = x1 > 0.f ? x1 : (__expf(x1) - 1.f);
        x0 *= dn; x1 *= dn;                        // fold dinv[node] for GCN
        unsigned int o = (unsigned int)f2bf(x0) | ((unsigned int)f2bf(x1) << 16);
        op[off[k]] = o;
    }
}

// ---------------------------------------------------------------------------
// GCN aggregation v4: h' already dinv-scaled -> plain sum, then * dinv[node].
// ---------------------------------------------------------------------------
__global__ __launch_bounds__(256) void gcn_agg_kernel(
        const unsigned short* __restrict__ h, const int* __restrict__ row_ptr,
        const int* __restrict__ col, const float* __restrict__ dinv,
        unsigned short* __restrict__ agg) {
    int node = blockIdx.x * 4 + (threadIdx.x >> 6);
    if (node >= NNODES) return;
    int ln = threadIdx.x & 63;
    bool hasC = ln < 3;
    float accA[8] = {}, accB[4] = {}, accC[4] = {};
    int e0 = row_ptr[node], e1 = row_ptr[node + 1];
    int e = e0;
    int jn = (e < e1) ? col[e] : 0;
    for (; e < e1; ) {
        int j = __builtin_amdgcn_readfirstlane(jn);
        ++e;
        jn = (e < e1) ? col[e] : 0;
        const unsigned short* hr = h + (size_t)j * HCDIM;
        bf16x8_t u = *(const bf16x8_t*)(hr + 8 * ln);
        ushort4 v4 = *(const ushort4*)(hr + 512 + 4 * ln);
        ushort4 w4 = hasC ? *(const ushort4*)(hr + 768 + 4 * ln) : make_ushort4(0, 0, 0, 0);
        #pragma unroll
        for (int k = 0; k < 8; k++) accA[k] += bf2f((unsigned short)u[k]);
        accB[0] += bf2f(v4.x);
        accB[1] += bf2f(v4.y);
        accB[2] += bf2f(v4.z);
        accB[3] += bf2f(v4.w);
        accC[0] += bf2f(w4.x);
        accC[1] += bf2f(w4.y);
        accC[2] += bf2f(w4.z);
        accC[3] += bf2f(w4.w);
    }
    float di = dinv[node];
    unsigned short* ar = agg + (size_t)node * HCDIM;
    ushort4 o1, o2, ob;
    o1.x = f2bf(accA[0] * di); o1.y = f2bf(accA[1] * di);
    o1.z = f2bf(accA[2] * di); o1.w = f2bf(accA[3] * di);
    o2.x = f2bf(accA[4] * di); o2.y = f2bf(accA[5] * di);
    o2.z = f2bf(accA[6] * di); o2.w = f2bf(accA[7] * di);
    ob.x = f2bf(accB[0] * di); ob.y = f2bf(accB[1] * di);
    ob.z = f2bf(accB[2] * di); ob.w = f2bf(accB[3] * di);
    *(ushort4*)(ar + 8 * ln) = o1;
    *(ushort4*)(ar + 8 * ln + 4) = o2;
    *(ushort4*)(ar + 512 + 4 * ln) = ob;
    if (hasC) {
        ushort4 oc;
        oc.x = f2bf(accC[0] * di); oc.y = f2bf(accC[1] * di);
        oc.z = f2bf(accC[2] * di); oc.w = f2bf(accC[3] * di);
        *(ushort4*)(ar + 768 + 4 * ln) = oc;
    }
}

// ---------------------------------------------------------------------------
// BT prep: BT[n][k] = bf16(W_gcn[k][n]), zero-padded to [NPAD][KPAD]
// ---------------------------------------------------------------------------
__global__ void btprep_kernel(const float* __restrict__ W, unsigned short* __restrict__ BT) {
    int idx = blockIdx.x * 256 + threadIdx.x;
    if (idx >= NPAD * KPAD) return;
    int n = idx / KPAD, k = idx - n * KPAD;
    float v = (n < HCDIM && k < HCDIM) ? W[(size_t)k * HCDIM + n] : 0.f;
    BT[idx] = f2bf(v);
}

// ---------------------------------------------------------------------------
// GEMM2 MFMA fused v4 (unchanged from round 9): BK=64, rotation swizzle,
// XCD-aware band mapping.
// ---------------------------------------------------------------------------
__global__ __launch_bounds__(256) void gemm2_pool_kernel(
        const unsigned short* __restrict__ A, const unsigned short* __restrict__ BT,
        const float* __restrict__ bias, const int* __restrict__ batch,
        float* __restrict__ out, int M) {
    int f = blockIdx.x;
    int xcd = f & 7, inner = f >> 3;
    int bq = inner / 7, colt = inner - 7 * bq;
    int band = 8 * bq + xcd;
    if (band >= (M + BM - 1) / BM) return;
    int bm = band * BM, bn = colt * BN;

    __shared__ unsigned short smem[2 * 128 * 64];
    unsigned short* As = smem;
    unsigned short* Bs = smem + 128 * 64;
    __shared__ int bsh[BM];

    int t = threadIdx.x;
    int lane = t & 63, w = t >> 6;

    if (t < BM) {
        int row = bm + t;
        bsh[t] = (row < M) ? batch[row] : -1;
    }

    int m16 = lane & 15, q = lane >> 4;
    int wr = (w >> 1) * 64, wc = (w & 1) * 64;

    int lrow8 = lane >> 3;
    int c8 = lane & 7;
    int gch = (c8 - lrow8) & 7;
    const unsigned short* gA = A  + (size_t)(bm + 32 * w + lrow8) * HCDIM + gch * 8;
    const unsigned short* gB = BT + (size_t)(bn + 32 * w + lrow8) * KPAD  + gch * 8;
    unsigned short* lA = As + (32 * w) * 64;
    unsigned short* lB = Bs + (32 * w) * 64;

    f32x4_t acc[4][4];
    #pragma unroll
    for (int i = 0; i < 4; i++)
        #pragma unroll
        for (int j = 0; j < 4; j++)
            acc[i][j] = (f32x4_t)(0.f);

    for (int k0 = 0; k0 < KPAD; k0 += BK) {
        __syncthreads();
        #pragma unroll
        for (int ib = 0; ib < 4; ib++) {
            async_ld16(gA + (size_t)(8 * ib) * HCDIM + k0, lA + (8 * ib) * 64);
            async_ld16(gB + (size_t)(8 * ib) * KPAD  + k0, lB + (8 * ib) * 64);
        }
        __syncthreads();

        #pragma unroll
        for (int half = 0; half < 2; half++) {
            bf16x8_t af[4], bf[4];
            #pragma unroll
            for (int i = 0; i < 4; i++) {
                int row = wr + i * 16 + m16;
                af[i] = *(const bf16x8_t*)&As[row * 64 + ((4 * half + q + row) & 7) * 8];
            }
            #pragma unroll
            for (int j = 0; j < 4; j++) {
                int row = wc + j * 16 + m16;
                bf[j] = *(const bf16x8_t*)&Bs[row * 64 + ((4 * half + q + row) & 7) * 8];
            }
            #pragma unroll
            for (int i = 0; i < 4; i++)
                #pragma unroll
                for (int j = 0; j < 4; j++)
                    acc[i][j] = __builtin_amdgcn_mfma_f32_16x16x32_bf16(af[i], bf[j], acc[i][j], 0, 0, 0);
        }
    }

    float bvj[4];
    #pragma unroll
    for (int j = 0; j < 4; j++) {
        int gcc = bn + wc + j * 16 + m16;
        bvj[j] = (gcc < HCDIM) ? bias[gcc] : 0.f;
    }

    #pragma unroll
    for (int p = 0; p < 2; p++) {
        __syncthreads();
        if ((w >> 1) == p) {
            #pragma unroll
            for (int i = 0; i < 4; i++) {
                #pragma unroll
                for (int j = 0; j < 4; j++) {
                    int colc = wc + j * 16 + m16;
                    ushort4 o;
                    float v0 = acc[i][j][0] + bvj[j];
                    float v1 = acc[i][j][1] + bvj[j];
                    float v2 = acc[i][j][2] + bvj[j];
                    float v3 = acc[i][j][3] + bvj[j];
                    o.x = f2bf(v0 > 0.f ? v0 : 0.f);
                    o.y = f2bf(v1 > 0.f ? v1 : 0.f);
                    o.z = f2bf(v2 > 0.f ? v2 : 0.f);
                    o.w = f2bf(v3 > 0.f ? v3 : 0.f);
                    *(ushort4*)&smem[colc * LDT + i * 16 + q * 4] = o;
                }
            }
        }
        __syncthreads();
        int colp = t & 127;
        int rb = (t >> 7) * 32;
        int gc = bn + colp;
        if (gc < HCDIM) {
            int cur = -1; float mx = 0.f, sm = 0.f;
            bool done = false;
            for (int rr = rb; rr < rb + 32 && !done; rr += 4) {
                ushort4 u = *(const ushort4*)&smem[colp * LDT + rr];
                unsigned short us[4] = {u.x, u.y, u.z, u.w};
                #pragma unroll
                for (int s2 = 0; s2 < 4; s2++) {
                    int b = bsh[64 * p + rr + s2];
                    if (b < 0) { done = true; break; }
                    float v = bf2f(us[s2]);
                    if (b != cur) {
                        if (cur >= 0) {
                            atomicMax((int*)(out + (size_t)cur * (2 * HCDIM) + gc), __float_as_int(mx));
                            atomicAdd(out + (size_t)cur * (2 * HCDIM) + HCDIM + gc, sm);
                        }
                        cur = b; mx = v; sm = v;
                    } else { mx = fmaxf(mx, v); sm += v; }
                }
            }
            if (cur >= 0) {
                atomicMax((int*)(out + (size_t)cur * (2 * HCDIM) + gc), __float_as_int(mx));
                atomicAdd(out + (size_t)cur * (2 * HCDIM) + HCDIM + gc, sm);
            }
        }
    }
}

// divide the mean slots by counts
__global__ void finalize_kernel(float* __restrict__ out, const int* __restrict__ bst) {
    int i = blockIdx.x * blockDim.x + threadIdx.x;
    if (i >= NBATCH * HCDIM) return;
    int b = i / HCDIM, c = i - b * HCDIM;
    int cnt = bst[b + 1] - bst[b];
    out[(size_t)b * (2 * HCDIM) + HCDIM + c] /= (float)(cnt > 0 ? cnt : 1);
}

// ---------------------------------------------------------------------------
extern "C" void kernel_launch(void* const* d_in, const int* in_sizes, int n_in,
                              void* d_out, int out_size, void* d_ws, size_t ws_size,
                              hipStream_t stream) {
    const float* x       = (const float*)d_in[0];
    const int*   ei      = (const int*)d_in[1];
    const int*   batch   = (const int*)d_in[2];
    const float* W_l     = (const float*)d_in[3];
    const float* W_r     = (const float*)d_in[4];
    const float* att     = (const float*)d_in[5];
    const float* bias1   = (const float*)d_in[6];
    const float* W_gcn   = (const float*)d_in[7];
    const float* bias_gcn= (const float*)d_in[8];
    float* out = (float*)d_out;

    char* w = (char*)d_ws;
    const size_t BIGH = (size_t)NNODES * HCDIM * sizeof(unsigned short);  // 78,000,000
    unsigned short* xl  = (unsigned short*)(w);          // later reused as agg
    unsigned short* xr  = (unsigned short*)(w + BIGH);   // becomes h'; later BT
    unsigned short* agg = xl;
    unsigned short* BT  = xr;                            // h' dead after gcn_agg
    char* sm = w + 2 * BIGH;
    int*   rowp = (int*)(sm);                    sm += 50048 * 4;
    int*   col  = (int*)(sm);                    sm += 450048 * 4;
    float* dinv = (float*)(sm);                  sm += 50048 * 4;
    int*   bst  = (int*)(sm);                    sm += 512 * 4;
    int*   bsum = (int*)(sm);                    sm += 256 * 4;
    char* S = sm;                                sm += 426240;
    int*   deg  = (int*)(S);
    int*   curs = (int*)(S + 200192);
    unsigned short* Wc = (unsigned short*)(S);
    size_t needed = (size_t)(sm - (char*)d_ws);
    if (ws_size < needed) return;   // fail soft instead of OOB fault

    // --- zero-init (out for atomics + deg) ---
    zero_kernel<<<(NBATCH * 2 * HCDIM + 255) / 256, 256, 0, stream>>>(
        out, NBATCH * 2 * HCDIM, deg, NNODES);

    // --- CSR build ---
    {
        int eblocks = (ETOT + 255) / 256;
        int nblocks = (NNODES + 255) / 256;     // 196
        count_kernel<<<eblocks, 256, 0, stream>>>(ei, deg);
        scan1_kernel<<<nblocks, 256, 0, stream>>>(deg, rowp, bsum);
        scan2_kernel<<<1, 512, 0, stream>>>(bsum, rowp, nblocks, batch, bst);
        scan3_kernel<<<nblocks, 256, 0, stream>>>(rowp, bsum, curs, deg, dinv);
        fill_kernel<<<eblocks, 256, 0, stream>>>(ei, curs, col);
    }

    // --- Wc = [W_l|W_r]^T bf16 padded (overwrites deg/curs) ---
    wprep_kernel<<<(NP1 * KP1 + 255) / 256, 256, 0, stream>>>(W_l, W_r, Wc);

    // --- fused GEMM1 (MFMA): xl|xr = x @ [W_l|W_r] ---
    gemm1_kernel<<<(NNODES + 127) / 128, 256, 0, stream>>>(x, Wc, xl, xr, NNODES);

    // --- GATv2 + ELU (+dinv fold, writes h' over xr); 5 waves per 4 nodes ---
    {
        int waves = (NNODES / 4) * 5;          // 62500
        int blocks = waves / 4;                // 15625
        gat_kernel<<<blocks, 256, 0, stream>>>(xl, xr, rowp, col, att, bias1, dinv, xr);
    }

    // --- GCN aggregate (h' -> agg, overwrites xl space) ---
    gcn_agg_kernel<<<(NNODES + 3) / 4, 256, 0, stream>>>(xr, rowp, col, dinv, agg);

    // --- W_gcn^T -> bf16 padded (into xr region; h' is dead) ---
    btprep_kernel<<<(NPAD * KPAD + 255) / 256, 256, 0, stream>>>(W_gcn, BT);

    // --- GEMM2 (MFMA, XCD-swizzled flat grid) + bias + relu + fused pooling ---
    {
        int nb = (NNODES + BM - 1) / BM;       // 391
        int gx = 8 * ((nb + 7) / 8) * 7;       // 2744
        gemm2_pool_kernel<<<gx, 256, 0, stream>>>(agg, BT, bias_gcn, batch, out, NNODES);
    }

    // --- finalize means ---
    finalize_kernel<<<(NBATCH * HCDIM + 255) / 256, 256, 0, stream>>>(out, bst);
}